// Round 14
// baseline (632.834 us; speedup 1.0000x reference)
//
#include <hip/hip_runtime.h>
#include <hip/hip_bf16.h>
#include <math.h>

// ---------------------------------------------------------------------------
// GCN 2-layer forward on MI355X (gfx950).
// Inputs: x[N,128] f32, edge_index[2,E] int32, W1[128,128], b1[128],
//         W2[128,40], b2[40].  Output: log_softmax [N,40] f32.
// Round 14 (= Round 13 fixed): XCD-pinned feature-sliced pulls.
//   k_pull1 was gather-bound: 410MB logical gathers from 25.6MB T, but
//   per-XCD L2 (4MB) holds only ~16% -> 195MB L2-miss, HBM-rate 62us.
//   Fix: slice features 8x16 (32B/row-slice); block (blockIdx&7)=j gathers
//   only slice j (3.2MB, fits one XCD L2) -> gathers become L2 hits.
//   ecol re-read per slice via nontemporal loads; U written nontemporal.
//   Same for pull2 (5 slices of 8 classes, 1.6MB); log_softmax split into
//   separate in-place pass over out.
//   Compile fix: __builtin_nontemporal_store needs ext_vector_type, not
//   HIP_vector_type (uint4/float4) -> u32x4/f32x4 typedefs at store sites.
// ---------------------------------------------------------------------------

#define TILE_A 8192   // edges per binning block
#define RB 98         // rows per bucket (1021 buckets for N=100000)

typedef __attribute__((ext_vector_type(8))) short bf16x8;   // 8 bf16 = 4 VGPR
typedef __attribute__((ext_vector_type(4))) float f32x4;
typedef __attribute__((ext_vector_type(4))) unsigned int u32x4;

struct f8 { float v[8]; };

__device__ inline f8 unpack8(uint4 u) {
    f8 r;
    r.v[0] = __uint_as_float(u.x << 16);
    r.v[1] = __uint_as_float(u.x & 0xffff0000u);
    r.v[2] = __uint_as_float(u.y << 16);
    r.v[3] = __uint_as_float(u.y & 0xffff0000u);
    r.v[4] = __uint_as_float(u.z << 16);
    r.v[5] = __uint_as_float(u.z & 0xffff0000u);
    r.v[6] = __uint_as_float(u.w << 16);
    r.v[7] = __uint_as_float(u.w & 0xffff0000u);
    return r;
}

__device__ inline unsigned pack2(float a, float b) {  // a -> low half (RNE)
    __hip_bfloat16 ha = __float2bfloat16(a);
    __hip_bfloat16 hb = __float2bfloat16(b);
    unsigned short sa = *(unsigned short*)&ha;
    unsigned short sb = *(unsigned short*)&hb;
    return (unsigned)sa | ((unsigned)sb << 16);
}

__device__ inline short bfs(float f) {  // f32 -> bf16 bits (RNE)
    __hip_bfloat16 h = __float2bfloat16(f);
    return *(short*)&h;
}

__device__ inline bf16x8 to8(float4 p, float4 q) {
    bf16x8 v;
    v[0] = bfs(p.x); v[1] = bfs(p.y); v[2] = bfs(p.z); v[3] = bfs(p.w);
    v[4] = bfs(q.x); v[5] = bfs(q.y); v[6] = bfs(q.z); v[7] = bfs(q.w);
    return v;
}

__global__ __launch_bounds__(256) void k_zero(int* __restrict__ p, int n) {
    int i = blockIdx.x * 256 + threadIdx.x;
    if (i < n) p[i] = 0;
}

// bucket histogram over row index (LDS-aggregated)
__global__ __launch_bounds__(256) void k_prebin(const int* __restrict__ row,
                                                int* __restrict__ bktcnt,
                                                int E, int nbkt) {
    __shared__ int h[1024];
    int t = threadIdx.x;
    for (int j = t; j < 1024; j += 256) h[j] = 0;
    __syncthreads();
    int base = blockIdx.x * TILE_A;
    int lim = min(base + TILE_A, E);
    for (int i = base + t; i < lim; i += 256) atomicAdd(&h[row[i] / RB], 1);
    __syncthreads();
    for (int j = t; j < nbkt; j += 256)
        if (h[j]) atomicAdd(&bktcnt[j], h[j]);
}

// single-block scan of bucket counts -> gbase (exclusive), gcur (= gbase)
__global__ __launch_bounds__(1024) void k_bscan(const int* __restrict__ bktcnt,
                                                int* __restrict__ gbase,
                                                int* __restrict__ gcur, int nbkt) {
    __shared__ int l[1024];
    int t = threadIdx.x;
    int v = (t < nbkt) ? bktcnt[t] : 0;
    l[t] = v;
    __syncthreads();
#pragma unroll
    for (int o = 1; o < 1024; o <<= 1) {
        int u = (t >= o) ? l[t - o] : 0;
        __syncthreads();
        l[t] += u;
        __syncthreads();
    }
    if (t < nbkt) {
        int excl = l[t] - v;
        gbase[t] = excl;
        gcur[t] = excl;
        if (t == nbkt - 1) gbase[nbkt] = l[t];
    }
}

// partition edges into buckets as (r,c) records; LDS histogram ->
// one global tail-append atomic per (block, bucket) -> LDS cursor scatter.
__global__ __launch_bounds__(256) void k_binA(const int* __restrict__ ei,
                                              int* __restrict__ gcur,
                                              int2* __restrict__ brec, int E) {
    __shared__ int h[1024];
    __shared__ int cur[1024];
    int t = threadIdx.x;
    for (int j = t; j < 1024; j += 256) h[j] = 0;
    __syncthreads();
    int base = blockIdx.x * TILE_A;
    int lim = min(base + TILE_A, E);
    for (int i = base + t; i < lim; i += 256) atomicAdd(&h[ei[i] / RB], 1);
    __syncthreads();
    for (int j = t; j < 1024; j += 256)
        cur[j] = h[j] ? atomicAdd(&gcur[j], h[j]) : 0;
    __syncthreads();
    for (int i = base + t; i < lim; i += 256) {
        int r = ei[i];
        int pos = atomicAdd(&cur[r / RB], 1);
        brec[pos] = make_int2(r, ei[E + i]);
    }
}

// per-bucket degree count: LDS histogram, coalesced non-atomic deg write (+1 self loop)
__global__ __launch_bounds__(256) void k_count3(const int2* __restrict__ brec,
                                                const int* __restrict__ gbase,
                                                int* __restrict__ deg, int N) {
    __shared__ int h[RB];
    int k = blockIdx.x;
    int t = threadIdx.x;
    if (t < RB) h[t] = 0;
    __syncthreads();
    int s = gbase[k], e = gbase[k + 1];
    int r0 = k * RB;
    for (int i = s + t; i < e; i += 256) atomicAdd(&h[brec[i].x - r0], 1);
    __syncthreads();
    if (t < RB && r0 + t < N) deg[r0 + t] = h[t] + 1;
}

// block-level inclusive scan of (deg-1); partials to bsum; also dinv = rsqrt(deg)
__global__ __launch_bounds__(256) void k_scan1(const int* __restrict__ deg,
                                               int* __restrict__ tmp,
                                               int* __restrict__ bsum,
                                               float* __restrict__ dinv, int N) {
    __shared__ int l[256];
    int t = threadIdx.x;
    int i = blockIdx.x * 256 + t;
    int d = (i < N) ? deg[i] : 1;
    if (i < N) dinv[i] = rsqrtf((float)d);
    l[t] = (i < N) ? d - 1 : 0;
    __syncthreads();
#pragma unroll
    for (int o = 1; o < 256; o <<= 1) {
        int u = (t >= o) ? l[t - o] : 0;
        __syncthreads();
        l[t] += u;
        __syncthreads();
    }
    if (i < N) tmp[i] = l[t];
    if (t == 255) bsum[blockIdx.x] = l[255];
}

__global__ __launch_bounds__(1024) void k_scan2(int* __restrict__ bsum, int nb) {
    __shared__ int l[1024];
    int t = threadIdx.x;
    l[t] = (t < nb) ? bsum[t] : 0;
    __syncthreads();
#pragma unroll
    for (int o = 1; o < 1024; o <<= 1) {
        int u = (t >= o) ? l[t - o] : 0;
        __syncthreads();
        l[t] += u;
        __syncthreads();
    }
    if (t < nb) bsum[t] = l[t];
}

__global__ __launch_bounds__(256) void k_scan3(const int* __restrict__ deg,
                                               const int* __restrict__ tmp,
                                               const int* __restrict__ bsum,
                                               int* __restrict__ row_ptr, int N, int E) {
    int i = blockIdx.x * 256 + threadIdx.x;
    if (i >= N) return;
    int excl = tmp[i] - (deg[i] - 1) + (blockIdx.x ? bsum[blockIdx.x - 1] : 0);
    row_ptr[i] = excl;
    if (i == 0) row_ptr[N] = E;
}

// per-bucket CSR scatter: cursors in LDS, writes confined to the bucket's
// contiguous ecol window (~6KB) -> streaming, no global atomics.
__global__ __launch_bounds__(256) void k_csr3(const int2* __restrict__ brec,
                                              const int* __restrict__ gbase,
                                              const int* __restrict__ row_ptr,
                                              int* __restrict__ ecol, int N) {
    __shared__ int cur[RB];
    int k = blockIdx.x;
    int t = threadIdx.x;
    int r0 = k * RB;
    if (t < RB) cur[t] = (r0 + t < N) ? row_ptr[r0 + t] : 0;
    __syncthreads();
    int s = gbase[k], e = gbase[k + 1];
    for (int i = s + t; i < e; i += 256) {
        int2 rc = brec[i];
        int pos = atomicAdd(&cur[rc.x - r0], 1);
        ecol[pos] = rc.y;
    }
}

// Wt1[f][k] = bf16(W1[k][f])  (128x128)
__global__ __launch_bounds__(256) void k_wt1(const float* __restrict__ W,
                                             short* __restrict__ Wt) {
    int idx = blockIdx.x * 256 + threadIdx.x;  // 16384
    int k = idx >> 7, f = idx & 127;
    Wt[f * 128 + k] = bfs(W[k * 128 + f]);
}

// Wt2[f][k] = bf16(W2[k][f]) for f<40, else 0  (48x128, padded)
__global__ __launch_bounds__(256) void k_wt2(const float* __restrict__ W,
                                             short* __restrict__ Wt) {
    int idx = blockIdx.x * 256 + threadIdx.x;  // 6144
    int f = idx >> 7, k = idx & 127;
    Wt[idx] = (f < 40) ? bfs(W[k * 40 + f]) : (short)0;
}

// T[N,128](bf16) = bf16(X) @ bf16(W1) via MFMA. 128 nodes/block, 4 waves.
__global__ __launch_bounds__(256) void k_gemm1m(const float* __restrict__ x,
                                                const short* __restrict__ Wt,  // [128f][128k]
                                                short* __restrict__ Tb, int N) {
    int t = threadIdx.x;
    int wid = t >> 6, l = t & 63;
    int r = l & 15;          // A row / B col / D col
    int ko = (l >> 4) * 8;   // k offset within 32-chunk
    long long nb = (long long)blockIdx.x * 128 + wid * 32;

    bf16x8 a[2][4];
#pragma unroll
    for (int g = 0; g < 2; ++g) {
        long long n = nb + g * 16 + r;
        if (n >= N) n = N - 1;
        const float* xr = x + n * 128;
#pragma unroll
        for (int kc = 0; kc < 4; ++kc) {
            float4 p = *(const float4*)(xr + kc * 32 + ko);
            float4 q = *(const float4*)(xr + kc * 32 + ko + 4);
            a[g][kc] = to8(p, q);
        }
    }

    f32x4 acc[2][8];
#pragma unroll
    for (int g = 0; g < 2; ++g)
#pragma unroll
        for (int ft = 0; ft < 8; ++ft) acc[g][ft] = (f32x4){0.f, 0.f, 0.f, 0.f};

#pragma unroll
    for (int ft = 0; ft < 8; ++ft) {
        const short* wp = Wt + (ft * 16 + r) * 128 + ko;
#pragma unroll
        for (int kc = 0; kc < 4; ++kc) {
            bf16x8 b = *(const bf16x8*)(wp + kc * 32);
            acc[0][ft] = __builtin_amdgcn_mfma_f32_16x16x32_bf16(a[0][kc], b, acc[0][ft], 0, 0, 0);
            acc[1][ft] = __builtin_amdgcn_mfma_f32_16x16x32_bf16(a[1][kc], b, acc[1][ft], 0, 0, 0);
        }
    }

    int row0 = (l >> 4) * 4;  // D: col=r, row=row0+i
#pragma unroll
    for (int g = 0; g < 2; ++g) {
#pragma unroll
        for (int i = 0; i < 4; ++i) {
            long long n = nb + g * 16 + row0 + i;
            if (n < N) {
                short* orow = Tb + n * 128;
#pragma unroll
                for (int ft = 0; ft < 8; ++ft) orow[ft * 16 + r] = bfs(acc[g][ft][i]);
            }
        }
    }
}

// H2[N,40](bf16) = U[N,128](bf16) @ bf16(W2) via MFMA. Same tiling, 3 f-tiles.
__global__ __launch_bounds__(256) void k_gemm2m(const short* __restrict__ Ub,   // [N][128] bf16
                                                const short* __restrict__ Wt2,  // [48f][128k]
                                                short* __restrict__ H2b, int N) {
    int t = threadIdx.x;
    int wid = t >> 6, l = t & 63;
    int r = l & 15;
    int ko = (l >> 4) * 8;
    long long nb = (long long)blockIdx.x * 128 + wid * 32;

    bf16x8 a[2][4];
#pragma unroll
    for (int g = 0; g < 2; ++g) {
        long long n = nb + g * 16 + r;
        if (n >= N) n = N - 1;
        const short* ur = Ub + n * 128;
#pragma unroll
        for (int kc = 0; kc < 4; ++kc)
            a[g][kc] = *(const bf16x8*)(ur + kc * 32 + ko);
    }

    f32x4 acc[2][3];
#pragma unroll
    for (int g = 0; g < 2; ++g)
#pragma unroll
        for (int ft = 0; ft < 3; ++ft) acc[g][ft] = (f32x4){0.f, 0.f, 0.f, 0.f};

#pragma unroll
    for (int ft = 0; ft < 3; ++ft) {
        const short* wp = Wt2 + (ft * 16 + r) * 128 + ko;
#pragma unroll
        for (int kc = 0; kc < 4; ++kc) {
            bf16x8 b = *(const bf16x8*)(wp + kc * 32);
            acc[0][ft] = __builtin_amdgcn_mfma_f32_16x16x32_bf16(a[0][kc], b, acc[0][ft], 0, 0, 0);
            acc[1][ft] = __builtin_amdgcn_mfma_f32_16x16x32_bf16(a[1][kc], b, acc[1][ft], 0, 0, 0);
        }
    }

    int row0 = (l >> 4) * 4;
#pragma unroll
    for (int g = 0; g < 2; ++g) {
#pragma unroll
        for (int i = 0; i < 4; ++i) {
            long long n = nb + g * 16 + row0 + i;
            if (n < N) {
                short* orow = H2b + n * 40;
#pragma unroll
                for (int ft = 0; ft < 3; ++ft) {
                    int f = ft * 16 + r;
                    if (f < 40) orow[f] = bfs(acc[g][ft][i]);
                }
            }
        }
    }
}

// XCD-pinned sliced pull, layer 1. Slice j = blockIdx&7 covers features
// [j*16, j*16+16); 2 lanes/node, 128 nodes/block. T-slice = 3.2MB -> one L2.
__global__ __launch_bounds__(256) void k_pull1s(const uint4* __restrict__ Tb,
                                                const float* __restrict__ dinv,
                                                const int* __restrict__ row_ptr,
                                                const int* __restrict__ ecol,
                                                const float* __restrict__ b,
                                                unsigned* __restrict__ Ub, int N) {
    int j = blockIdx.x & 7;
    int n = (blockIdx.x >> 3) * 128 + (threadIdx.x >> 1);
    if (n >= N) return;
    int q = threadIdx.x & 1;
    int fo = j * 2 + q;  // uint4 index within the 16-uint4 row

    float dn = dinv[n];
    float ss = dn * dn;
    f8 s8 = unpack8(Tb[(size_t)n * 16 + fo]);
    float acc[8];
#pragma unroll
    for (int k = 0; k < 8; ++k) acc[k] = s8.v[k] * ss;

    int beg = row_ptr[n], end = row_ptr[n + 1];
    int i = beg;
    for (; i + 1 < end; i += 2) {
        int c0 = __builtin_nontemporal_load(ecol + i);
        int c1 = __builtin_nontemporal_load(ecol + i + 1);
        float w0 = dn * dinv[c0];
        float w1 = dn * dinv[c1];
        uint4 g0 = Tb[(size_t)c0 * 16 + fo];
        uint4 g1 = Tb[(size_t)c1 * 16 + fo];
        f8 a0 = unpack8(g0);
        f8 a1 = unpack8(g1);
#pragma unroll
        for (int k = 0; k < 8; ++k) acc[k] = fmaf(w0, a0.v[k], acc[k]);
#pragma unroll
        for (int k = 0; k < 8; ++k) acc[k] = fmaf(w1, a1.v[k], acc[k]);
    }
    if (i < end) {
        int c0 = __builtin_nontemporal_load(ecol + i);
        float w0 = dn * dinv[c0];
        f8 a0 = unpack8(Tb[(size_t)c0 * 16 + fo]);
#pragma unroll
        for (int k = 0; k < 8; ++k) acc[k] = fmaf(w0, a0.v[k], acc[k]);
    }

    float4 b0 = ((const float4*)b)[fo * 2];
    float4 b1v = ((const float4*)b)[fo * 2 + 1];
    acc[0] = fmaxf(acc[0] + b0.x, 0.f);
    acc[1] = fmaxf(acc[1] + b0.y, 0.f);
    acc[2] = fmaxf(acc[2] + b0.z, 0.f);
    acc[3] = fmaxf(acc[3] + b0.w, 0.f);
    acc[4] = fmaxf(acc[4] + b1v.x, 0.f);
    acc[5] = fmaxf(acc[5] + b1v.y, 0.f);
    acc[6] = fmaxf(acc[6] + b1v.z, 0.f);
    acc[7] = fmaxf(acc[7] + b1v.w, 0.f);

    u32x4 o;
    o.x = pack2(acc[0], acc[1]);
    o.y = pack2(acc[2], acc[3]);
    o.z = pack2(acc[4], acc[5]);
    o.w = pack2(acc[6], acc[7]);
    __builtin_nontemporal_store(o, (u32x4*)(Ub + ((size_t)n * 16 + fo) * 4));
}

// XCD-pinned sliced pull, layer 2. Slice j = blockIdx&7 < 5 covers classes
// [j*8, j*8+8); 1 lane/node, 256 nodes/block. H2-slice = 1.6MB -> one L2.
// Writes biased logits (f32) into out; log_softmax is a separate pass.
__global__ __launch_bounds__(256) void k_pull2s(const uint4* __restrict__ H2b,
                                                const float* __restrict__ dinv,
                                                const int* __restrict__ row_ptr,
                                                const int* __restrict__ ecol,
                                                const float* __restrict__ b2,
                                                float* __restrict__ out, int N) {
    int j = blockIdx.x & 7;
    if (j >= 5) return;
    int n = (blockIdx.x >> 3) * 256 + threadIdx.x;
    if (n >= N) return;

    float dn = dinv[n];
    float ss = dn * dn;
    f8 s8 = unpack8(H2b[(size_t)n * 5 + j]);
    float acc[8];
#pragma unroll
    for (int k = 0; k < 8; ++k) acc[k] = s8.v[k] * ss;

    int beg = row_ptr[n], end = row_ptr[n + 1];
    int i = beg;
    for (; i + 1 < end; i += 2) {
        int c0 = __builtin_nontemporal_load(ecol + i);
        int c1 = __builtin_nontemporal_load(ecol + i + 1);
        float w0 = dn * dinv[c0];
        float w1 = dn * dinv[c1];
        f8 a0 = unpack8(H2b[(size_t)c0 * 5 + j]);
        f8 a1 = unpack8(H2b[(size_t)c1 * 5 + j]);
#pragma unroll
        for (int k = 0; k < 8; ++k) acc[k] = fmaf(w0, a0.v[k], acc[k]);
#pragma unroll
        for (int k = 0; k < 8; ++k) acc[k] = fmaf(w1, a1.v[k], acc[k]);
    }
    if (i < end) {
        int c0 = __builtin_nontemporal_load(ecol + i);
        float w0 = dn * dinv[c0];
        f8 a0 = unpack8(H2b[(size_t)c0 * 5 + j]);
#pragma unroll
        for (int k = 0; k < 8; ++k) acc[k] = fmaf(w0, a0.v[k], acc[k]);
    }

    float4 b0 = ((const float4*)b2)[j * 2];
    float4 b1v = ((const float4*)b2)[j * 2 + 1];
    f32x4 o0 = {acc[0] + b0.x, acc[1] + b0.y, acc[2] + b0.z, acc[3] + b0.w};
    f32x4 o1 = {acc[4] + b1v.x, acc[5] + b1v.y, acc[6] + b1v.z, acc[7] + b1v.w};
    __builtin_nontemporal_store(o0, (f32x4*)(out + (size_t)n * 40 + j * 8));
    __builtin_nontemporal_store(o1, (f32x4*)(out + (size_t)n * 40 + j * 8 + 4));
}

// in-place log_softmax over 40 classes; 8 lanes/node, lanes q<5 hold 8 each.
__global__ __launch_bounds__(256) void k_lsm2(float* __restrict__ out, int N) {
    int tid = blockIdx.x * 256 + threadIdx.x;
    int n = tid >> 3;
    if (n >= N) return;
    int q = tid & 7;
    bool act = q < 5;

    float4 v0 = make_float4(0.f, 0.f, 0.f, 0.f), v1 = v0;
    float4* o4 = (float4*)out;
    if (act) {
        v0 = o4[(size_t)n * 10 + q * 2];
        v1 = o4[(size_t)n * 10 + q * 2 + 1];
    }
    float m = -INFINITY;
    if (act) {
        m = fmaxf(fmaxf(fmaxf(v0.x, v0.y), fmaxf(v0.z, v0.w)),
                  fmaxf(fmaxf(v1.x, v1.y), fmaxf(v1.z, v1.w)));
    }
#pragma unroll
    for (int o = 4; o > 0; o >>= 1) m = fmaxf(m, __shfl_xor(m, o, 8));
    float e = 0.f;
    if (act) {
        e = expf(v0.x - m) + expf(v0.y - m) + expf(v0.z - m) + expf(v0.w - m) +
            expf(v1.x - m) + expf(v1.y - m) + expf(v1.z - m) + expf(v1.w - m);
    }
#pragma unroll
    for (int o = 4; o > 0; o >>= 1) e += __shfl_xor(e, o, 8);
    float lg = m + logf(e);
    if (act) {
        o4[(size_t)n * 10 + q * 2] =
            make_float4(v0.x - lg, v0.y - lg, v0.z - lg, v0.w - lg);
        o4[(size_t)n * 10 + q * 2 + 1] =
            make_float4(v1.x - lg, v1.y - lg, v1.z - lg, v1.w - lg);
    }
}

extern "C" void kernel_launch(void* const* d_in, const int* in_sizes, int n_in,
                              void* d_out, int out_size, void* d_ws, size_t ws_size,
                              hipStream_t stream) {
    const float* x  = (const float*)d_in[0];
    const int*   ei = (const int*)d_in[1];   // integer inputs arrive as int32
    const float* W1 = (const float*)d_in[2];
    const float* b1 = (const float*)d_in[3];
    const float* W2 = (const float*)d_in[4];
    const float* b2 = (const float*)d_in[5];
    float* out = (float*)d_out;

    const int N = in_sizes[0] / 128;  // 100000
    const int E = in_sizes[1] / 2;    // 1600000
    const int nbkt = (N + RB - 1) / RB;  // 1021 (<= 1024 required)

    // workspace layout (~83 MB; ws proven >= 120 MB in round 2/3)
    char* ws = (char*)d_ws;
    int*   deg     = (int*)(ws);                          // N ints
    float* dinv    = (float*)(ws + (512 << 10));          // N f32
    int*   row_ptr = (int*)(ws + (1 << 20));              // N+1
    int*   bsum    = (int*)(ws + (1536 << 10));           // <=1024
    int*   tmp     = (int*)(ws + (1600 << 10));           // N ints
    int*   bktcnt  = (int*)(ws + (2100 << 10));           // 1024
    int*   gcur    = (int*)(ws + (2100 << 10) + 4096);    // 1024
    int*   gbase   = (int*)(ws + (2100 << 10) + 8192);    // 1025
    short* Wt1     = (short*)(ws + (2200 << 10));         // 128x128 bf16 = 32 KB
    short* Wt2     = (short*)(ws + (2300 << 10));         // 48x128 bf16 = 12 KB
    int*   ecol    = (int*)(ws + (3 << 20));              // E ints = 6.4 MB
    int2*  brec    = (int2*)(ws + (10 << 20));            // E int2 = 12.8 MB
    uint4* H2b     = (uint4*)(ws + (23 << 20));           // N*40 bf16 = 8 MB
    unsigned* Tb   = (unsigned*)(ws + (31 << 20));        // N*128 bf16 = 25.6 MB
    unsigned* Ub   = (unsigned*)(ws + (57 << 20));        // N*128 bf16 = 25.6 MB

    int nb = (N + 255) / 256;
    int na = (E + TILE_A - 1) / TILE_A;
    int ng = (N + 127) / 128;  // MFMA gemm blocks

    k_zero<<<4, 256, 0, stream>>>(bktcnt, 1024);
    k_prebin<<<na, 256, 0, stream>>>(ei, bktcnt, E, nbkt);
    k_bscan<<<1, 1024, 0, stream>>>(bktcnt, gbase, gcur, nbkt);
    k_binA<<<na, 256, 0, stream>>>(ei, gcur, brec, E);
    k_count3<<<nbkt, 256, 0, stream>>>(brec, gbase, deg, N);
    k_scan1<<<nb, 256, 0, stream>>>(deg, tmp, bsum, dinv, N);
    k_scan2<<<1, 1024, 0, stream>>>(bsum, nb);
    k_scan3<<<nb, 256, 0, stream>>>(deg, tmp, bsum, row_ptr, N, E);
    k_csr3<<<nbkt, 256, 0, stream>>>(brec, gbase, row_ptr, ecol, N);

    k_wt1<<<64, 256, 0, stream>>>(W1, Wt1);
    k_wt2<<<24, 256, 0, stream>>>(W2, Wt2);

    k_gemm1m<<<ng, 256, 0, stream>>>(x, Wt1, (short*)Tb, N);
    k_pull1s<<<((N + 127) / 128) * 8, 256, 0, stream>>>(
        (const uint4*)Tb, dinv, row_ptr, ecol, b1, Ub, N);
    k_gemm2m<<<ng, 256, 0, stream>>>((const short*)Ub, Wt2, (short*)H2b, N);
    k_pull2s<<<((N + 255) / 256) * 8, 256, 0, stream>>>(
        H2b, dinv, row_ptr, ecol, b2, out, N);
    k_lsm2<<<((long long)N * 8 + 255) / 256, 256, 0, stream>>>(out, N);
}

// Round 15
// 227.229 us; speedup vs baseline: 2.7850x; 2.7850x over previous
//
#include <hip/hip_runtime.h>
#include <hip/hip_bf16.h>
#include <math.h>

// ---------------------------------------------------------------------------
// GCN 2-layer forward on MI355X (gfx950).
// Inputs: x[N,128] f32, edge_index[2,E] int32, W1[128,128], b1[128],
//         W2[128,40], b2[40].  Output: log_softmax [N,40] f32.
// Round 15: REVERT round-14 column-slicing (strided slices don't shrink a
//   line-granular working set: FETCH went 195->867MB). Back to round-12
//   pulls + one targeted change: CSR payload is packed erec=(col, weight)
//   int2, built in k_csr3. This cuts the pull edge-loop dependency chain
//   from 3 loads (ecol -> dinv[c] -> T[c]) to 2 (erec -> T[c]) -- pull1 was
//   latency-chain bound (VALUBusy 8.5%, 3.6TB/s on an L3-resident gather).
// ---------------------------------------------------------------------------

#define TILE_A 8192   // edges per binning block
#define RB 98         // rows per bucket (1021 buckets for N=100000)

typedef __attribute__((ext_vector_type(8))) short bf16x8;   // 8 bf16 = 4 VGPR
typedef __attribute__((ext_vector_type(4))) float f32x4;

struct f8 { float v[8]; };

__device__ inline f8 unpack8(uint4 u) {
    f8 r;
    r.v[0] = __uint_as_float(u.x << 16);
    r.v[1] = __uint_as_float(u.x & 0xffff0000u);
    r.v[2] = __uint_as_float(u.y << 16);
    r.v[3] = __uint_as_float(u.y & 0xffff0000u);
    r.v[4] = __uint_as_float(u.z << 16);
    r.v[5] = __uint_as_float(u.z & 0xffff0000u);
    r.v[6] = __uint_as_float(u.w << 16);
    r.v[7] = __uint_as_float(u.w & 0xffff0000u);
    return r;
}

__device__ inline unsigned pack2(float a, float b) {  // a -> low half (RNE)
    __hip_bfloat16 ha = __float2bfloat16(a);
    __hip_bfloat16 hb = __float2bfloat16(b);
    unsigned short sa = *(unsigned short*)&ha;
    unsigned short sb = *(unsigned short*)&hb;
    return (unsigned)sa | ((unsigned)sb << 16);
}

__device__ inline short bfs(float f) {  // f32 -> bf16 bits (RNE)
    __hip_bfloat16 h = __float2bfloat16(f);
    return *(short*)&h;
}

__device__ inline bf16x8 to8(float4 p, float4 q) {
    bf16x8 v;
    v[0] = bfs(p.x); v[1] = bfs(p.y); v[2] = bfs(p.z); v[3] = bfs(p.w);
    v[4] = bfs(q.x); v[5] = bfs(q.y); v[6] = bfs(q.z); v[7] = bfs(q.w);
    return v;
}

__global__ __launch_bounds__(256) void k_zero(int* __restrict__ p, int n) {
    int i = blockIdx.x * 256 + threadIdx.x;
    if (i < n) p[i] = 0;
}

// bucket histogram over row index (LDS-aggregated)
__global__ __launch_bounds__(256) void k_prebin(const int* __restrict__ row,
                                                int* __restrict__ bktcnt,
                                                int E, int nbkt) {
    __shared__ int h[1024];
    int t = threadIdx.x;
    for (int j = t; j < 1024; j += 256) h[j] = 0;
    __syncthreads();
    int base = blockIdx.x * TILE_A;
    int lim = min(base + TILE_A, E);
    for (int i = base + t; i < lim; i += 256) atomicAdd(&h[row[i] / RB], 1);
    __syncthreads();
    for (int j = t; j < nbkt; j += 256)
        if (h[j]) atomicAdd(&bktcnt[j], h[j]);
}

// single-block scan of bucket counts -> gbase (exclusive), gcur (= gbase)
__global__ __launch_bounds__(1024) void k_bscan(const int* __restrict__ bktcnt,
                                                int* __restrict__ gbase,
                                                int* __restrict__ gcur, int nbkt) {
    __shared__ int l[1024];
    int t = threadIdx.x;
    int v = (t < nbkt) ? bktcnt[t] : 0;
    l[t] = v;
    __syncthreads();
#pragma unroll
    for (int o = 1; o < 1024; o <<= 1) {
        int u = (t >= o) ? l[t - o] : 0;
        __syncthreads();
        l[t] += u;
        __syncthreads();
    }
    if (t < nbkt) {
        int excl = l[t] - v;
        gbase[t] = excl;
        gcur[t] = excl;
        if (t == nbkt - 1) gbase[nbkt] = l[t];
    }
}

// partition edges into buckets as (r,c) records; LDS histogram ->
// one global tail-append atomic per (block, bucket) -> LDS cursor scatter.
__global__ __launch_bounds__(256) void k_binA(const int* __restrict__ ei,
                                              int* __restrict__ gcur,
                                              int2* __restrict__ brec, int E) {
    __shared__ int h[1024];
    __shared__ int cur[1024];
    int t = threadIdx.x;
    for (int j = t; j < 1024; j += 256) h[j] = 0;
    __syncthreads();
    int base = blockIdx.x * TILE_A;
    int lim = min(base + TILE_A, E);
    for (int i = base + t; i < lim; i += 256) atomicAdd(&h[ei[i] / RB], 1);
    __syncthreads();
    for (int j = t; j < 1024; j += 256)
        cur[j] = h[j] ? atomicAdd(&gcur[j], h[j]) : 0;
    __syncthreads();
    for (int i = base + t; i < lim; i += 256) {
        int r = ei[i];
        int pos = atomicAdd(&cur[r / RB], 1);
        brec[pos] = make_int2(r, ei[E + i]);
    }
}

// per-bucket degree count: LDS histogram, coalesced non-atomic deg write (+1 self loop)
__global__ __launch_bounds__(256) void k_count3(const int2* __restrict__ brec,
                                                const int* __restrict__ gbase,
                                                int* __restrict__ deg, int N) {
    __shared__ int h[RB];
    int k = blockIdx.x;
    int t = threadIdx.x;
    if (t < RB) h[t] = 0;
    __syncthreads();
    int s = gbase[k], e = gbase[k + 1];
    int r0 = k * RB;
    for (int i = s + t; i < e; i += 256) atomicAdd(&h[brec[i].x - r0], 1);
    __syncthreads();
    if (t < RB && r0 + t < N) deg[r0 + t] = h[t] + 1;
}

// block-level inclusive scan of (deg-1); partials to bsum; also dinv = rsqrt(deg)
__global__ __launch_bounds__(256) void k_scan1(const int* __restrict__ deg,
                                               int* __restrict__ tmp,
                                               int* __restrict__ bsum,
                                               float* __restrict__ dinv, int N) {
    __shared__ int l[256];
    int t = threadIdx.x;
    int i = blockIdx.x * 256 + t;
    int d = (i < N) ? deg[i] : 1;
    if (i < N) dinv[i] = rsqrtf((float)d);
    l[t] = (i < N) ? d - 1 : 0;
    __syncthreads();
#pragma unroll
    for (int o = 1; o < 256; o <<= 1) {
        int u = (t >= o) ? l[t - o] : 0;
        __syncthreads();
        l[t] += u;
        __syncthreads();
    }
    if (i < N) tmp[i] = l[t];
    if (t == 255) bsum[blockIdx.x] = l[255];
}

__global__ __launch_bounds__(1024) void k_scan2(int* __restrict__ bsum, int nb) {
    __shared__ int l[1024];
    int t = threadIdx.x;
    l[t] = (t < nb) ? bsum[t] : 0;
    __syncthreads();
#pragma unroll
    for (int o = 1; o < 1024; o <<= 1) {
        int u = (t >= o) ? l[t - o] : 0;
        __syncthreads();
        l[t] += u;
        __syncthreads();
    }
    if (t < nb) bsum[t] = l[t];
}

__global__ __launch_bounds__(256) void k_scan3(const int* __restrict__ deg,
                                               const int* __restrict__ tmp,
                                               const int* __restrict__ bsum,
                                               int* __restrict__ row_ptr, int N, int E) {
    int i = blockIdx.x * 256 + threadIdx.x;
    if (i >= N) return;
    int excl = tmp[i] - (deg[i] - 1) + (blockIdx.x ? bsum[blockIdx.x - 1] : 0);
    row_ptr[i] = excl;
    if (i == 0) row_ptr[N] = E;
}

// per-bucket CSR scatter: cursors in LDS, writes packed (col, weight) records
// into the bucket's contiguous erec window -> streaming, no global atomics.
// weight = dinv[r]*dinv[c] precomputed here so pulls load it fused with col.
__global__ __launch_bounds__(256) void k_csr3(const int2* __restrict__ brec,
                                              const int* __restrict__ gbase,
                                              const int* __restrict__ row_ptr,
                                              const float* __restrict__ dinv,
                                              int2* __restrict__ erec, int N) {
    __shared__ int cur[RB];
    int k = blockIdx.x;
    int t = threadIdx.x;
    int r0 = k * RB;
    if (t < RB) cur[t] = (r0 + t < N) ? row_ptr[r0 + t] : 0;
    __syncthreads();
    int s = gbase[k], e = gbase[k + 1];
    for (int i = s + t; i < e; i += 256) {
        int2 rc = brec[i];
        int pos = atomicAdd(&cur[rc.x - r0], 1);
        float w = dinv[rc.x] * dinv[rc.y];
        erec[pos] = make_int2(rc.y, __float_as_int(w));
    }
}

// Wt1[f][k] = bf16(W1[k][f])  (128x128)
__global__ __launch_bounds__(256) void k_wt1(const float* __restrict__ W,
                                             short* __restrict__ Wt) {
    int idx = blockIdx.x * 256 + threadIdx.x;  // 16384
    int k = idx >> 7, f = idx & 127;
    Wt[f * 128 + k] = bfs(W[k * 128 + f]);
}

// Wt2[f][k] = bf16(W2[k][f]) for f<40, else 0  (48x128, padded)
__global__ __launch_bounds__(256) void k_wt2(const float* __restrict__ W,
                                             short* __restrict__ Wt) {
    int idx = blockIdx.x * 256 + threadIdx.x;  // 6144
    int f = idx >> 7, k = idx & 127;
    Wt[idx] = (f < 40) ? bfs(W[k * 40 + f]) : (short)0;
}

// T[N,128](bf16) = bf16(X) @ bf16(W1) via MFMA. 128 nodes/block, 4 waves.
__global__ __launch_bounds__(256) void k_gemm1m(const float* __restrict__ x,
                                                const short* __restrict__ Wt,  // [128f][128k]
                                                short* __restrict__ Tb, int N) {
    int t = threadIdx.x;
    int wid = t >> 6, l = t & 63;
    int r = l & 15;          // A row / B col / D col
    int ko = (l >> 4) * 8;   // k offset within 32-chunk
    long long nb = (long long)blockIdx.x * 128 + wid * 32;

    bf16x8 a[2][4];
#pragma unroll
    for (int g = 0; g < 2; ++g) {
        long long n = nb + g * 16 + r;
        if (n >= N) n = N - 1;
        const float* xr = x + n * 128;
#pragma unroll
        for (int kc = 0; kc < 4; ++kc) {
            float4 p = *(const float4*)(xr + kc * 32 + ko);
            float4 q = *(const float4*)(xr + kc * 32 + ko + 4);
            a[g][kc] = to8(p, q);
        }
    }

    f32x4 acc[2][8];
#pragma unroll
    for (int g = 0; g < 2; ++g)
#pragma unroll
        for (int ft = 0; ft < 8; ++ft) acc[g][ft] = (f32x4){0.f, 0.f, 0.f, 0.f};

#pragma unroll
    for (int ft = 0; ft < 8; ++ft) {
        const short* wp = Wt + (ft * 16 + r) * 128 + ko;
#pragma unroll
        for (int kc = 0; kc < 4; ++kc) {
            bf16x8 b = *(const bf16x8*)(wp + kc * 32);
            acc[0][ft] = __builtin_amdgcn_mfma_f32_16x16x32_bf16(a[0][kc], b, acc[0][ft], 0, 0, 0);
            acc[1][ft] = __builtin_amdgcn_mfma_f32_16x16x32_bf16(a[1][kc], b, acc[1][ft], 0, 0, 0);
        }
    }

    int row0 = (l >> 4) * 4;  // D: col=r, row=row0+i
#pragma unroll
    for (int g = 0; g < 2; ++g) {
#pragma unroll
        for (int i = 0; i < 4; ++i) {
            long long n = nb + g * 16 + row0 + i;
            if (n < N) {
                short* orow = Tb + n * 128;
#pragma unroll
                for (int ft = 0; ft < 8; ++ft) orow[ft * 16 + r] = bfs(acc[g][ft][i]);
            }
        }
    }
}

// H2[N,40](bf16) = U[N,128](bf16) @ bf16(W2) via MFMA. Same tiling, 3 f-tiles.
__global__ __launch_bounds__(256) void k_gemm2m(const short* __restrict__ Ub,   // [N][128] bf16
                                                const short* __restrict__ Wt2,  // [48f][128k]
                                                short* __restrict__ H2b, int N) {
    int t = threadIdx.x;
    int wid = t >> 6, l = t & 63;
    int r = l & 15;
    int ko = (l >> 4) * 8;
    long long nb = (long long)blockIdx.x * 128 + wid * 32;

    bf16x8 a[2][4];
#pragma unroll
    for (int g = 0; g < 2; ++g) {
        long long n = nb + g * 16 + r;
        if (n >= N) n = N - 1;
        const short* ur = Ub + n * 128;
#pragma unroll
        for (int kc = 0; kc < 4; ++kc)
            a[g][kc] = *(const bf16x8*)(ur + kc * 32 + ko);
    }

    f32x4 acc[2][3];
#pragma unroll
    for (int g = 0; g < 2; ++g)
#pragma unroll
        for (int ft = 0; ft < 3; ++ft) acc[g][ft] = (f32x4){0.f, 0.f, 0.f, 0.f};

#pragma unroll
    for (int ft = 0; ft < 3; ++ft) {
        const short* wp = Wt2 + (ft * 16 + r) * 128 + ko;
#pragma unroll
        for (int kc = 0; kc < 4; ++kc) {
            bf16x8 b = *(const bf16x8*)(wp + kc * 32);
            acc[0][ft] = __builtin_amdgcn_mfma_f32_16x16x32_bf16(a[0][kc], b, acc[0][ft], 0, 0, 0);
            acc[1][ft] = __builtin_amdgcn_mfma_f32_16x16x32_bf16(a[1][kc], b, acc[1][ft], 0, 0, 0);
        }
    }

    int row0 = (l >> 4) * 4;
#pragma unroll
    for (int g = 0; g < 2; ++g) {
#pragma unroll
        for (int i = 0; i < 4; ++i) {
            long long n = nb + g * 16 + row0 + i;
            if (n < N) {
                short* orow = H2b + n * 40;
#pragma unroll
                for (int ft = 0; ft < 3; ++ft) {
                    int f = ft * 16 + r;
                    if (f < 40) orow[f] = bfs(acc[g][ft][i]);
                }
            }
        }
    }
}

// U[n](bf16) = relu( dinv^2*T[n] + sum_e w_e*T[c_e] + b1 )
// 16 lanes/node, 8 bf16 features per lane (uint4); edge loop 4x unrolled.
// erec = (col, weight): one 8B load gives both -> 2-step dependency chain.
__global__ __launch_bounds__(256) void k_pull1(const uint4* __restrict__ Tb,
                                               const float* __restrict__ dinv,
                                               const int* __restrict__ row_ptr,
                                               const int2* __restrict__ erec,
                                               const float* __restrict__ b,
                                               uint4* __restrict__ Ub, int N) {
    int tid = blockIdx.x * 256 + threadIdx.x;
    int n = tid >> 4;
    if (n >= N) return;
    int q = tid & 15;

    float dn = dinv[n];
    float ss = dn * dn;
    f8 s8 = unpack8(Tb[(size_t)n * 16 + q]);
    float acc[8];
#pragma unroll
    for (int j = 0; j < 8; ++j) acc[j] = s8.v[j] * ss;

    int beg = row_ptr[n], end = row_ptr[n + 1];
    int i = beg;
    for (; i + 3 < end; i += 4) {
        int2 e0 = erec[i];
        int2 e1 = erec[i + 1];
        int2 e2 = erec[i + 2];
        int2 e3 = erec[i + 3];
        float w0 = __int_as_float(e0.y);
        float w1 = __int_as_float(e1.y);
        float w2 = __int_as_float(e2.y);
        float w3 = __int_as_float(e3.y);
        uint4 g0 = Tb[(size_t)e0.x * 16 + q];
        uint4 g1 = Tb[(size_t)e1.x * 16 + q];
        uint4 g2 = Tb[(size_t)e2.x * 16 + q];
        uint4 g3 = Tb[(size_t)e3.x * 16 + q];
        f8 a0 = unpack8(g0);
        f8 a1 = unpack8(g1);
        f8 a2 = unpack8(g2);
        f8 a3 = unpack8(g3);
#pragma unroll
        for (int j = 0; j < 8; ++j) acc[j] = fmaf(w0, a0.v[j], acc[j]);
#pragma unroll
        for (int j = 0; j < 8; ++j) acc[j] = fmaf(w1, a1.v[j], acc[j]);
#pragma unroll
        for (int j = 0; j < 8; ++j) acc[j] = fmaf(w2, a2.v[j], acc[j]);
#pragma unroll
        for (int j = 0; j < 8; ++j) acc[j] = fmaf(w3, a3.v[j], acc[j]);
    }
    for (; i < end; ++i) {
        int2 e0 = erec[i];
        float w0 = __int_as_float(e0.y);
        f8 a0 = unpack8(Tb[(size_t)e0.x * 16 + q]);
#pragma unroll
        for (int j = 0; j < 8; ++j) acc[j] = fmaf(w0, a0.v[j], acc[j]);
    }

    float4 b0 = ((const float4*)b)[q * 2];
    float4 b1v = ((const float4*)b)[q * 2 + 1];
    acc[0] = fmaxf(acc[0] + b0.x, 0.f);
    acc[1] = fmaxf(acc[1] + b0.y, 0.f);
    acc[2] = fmaxf(acc[2] + b0.z, 0.f);
    acc[3] = fmaxf(acc[3] + b0.w, 0.f);
    acc[4] = fmaxf(acc[4] + b1v.x, 0.f);
    acc[5] = fmaxf(acc[5] + b1v.y, 0.f);
    acc[6] = fmaxf(acc[6] + b1v.z, 0.f);
    acc[7] = fmaxf(acc[7] + b1v.w, 0.f);

    uint4 o;
    o.x = pack2(acc[0], acc[1]);
    o.y = pack2(acc[2], acc[3]);
    o.z = pack2(acc[4], acc[5]);
    o.w = pack2(acc[6], acc[7]);
    Ub[(size_t)n * 16 + q] = o;
}

// out[n] = log_softmax( dinv^2*H2[n] + sum w_e*H2[c_e] + b2 )  (f32 out)
// 8 lanes/node; lanes q<5 hold 8 classes each (uint4 of bf16).
__global__ __launch_bounds__(256) void k_pull2(const uint4* __restrict__ H2b,
                                               const float* __restrict__ dinv,
                                               const int* __restrict__ row_ptr,
                                               const int2* __restrict__ erec,
                                               const float* __restrict__ b2,
                                               float* __restrict__ out, int N) {
    int tid = blockIdx.x * 256 + threadIdx.x;
    int n = tid >> 3;
    if (n >= N) return;
    int q = tid & 7;
    bool act = q < 5;

    float dn = dinv[n];
    float ss = dn * dn;
    float acc[8];
#pragma unroll
    for (int j = 0; j < 8; ++j) acc[j] = 0.f;
    if (act) {
        f8 s8 = unpack8(H2b[(size_t)n * 5 + q]);
#pragma unroll
        for (int j = 0; j < 8; ++j) acc[j] = s8.v[j] * ss;
    }
    int beg = row_ptr[n], end = row_ptr[n + 1];
    int i = beg;
    for (; i + 1 < end; i += 2) {
        int2 e0 = erec[i];
        int2 e1 = erec[i + 1];
        if (act) {
            float w0 = __int_as_float(e0.y);
            float w1 = __int_as_float(e1.y);
            f8 a0 = unpack8(H2b[(size_t)e0.x * 5 + q]);
            f8 a1 = unpack8(H2b[(size_t)e1.x * 5 + q]);
#pragma unroll
            for (int j = 0; j < 8; ++j) acc[j] = fmaf(w0, a0.v[j], acc[j]);
#pragma unroll
            for (int j = 0; j < 8; ++j) acc[j] = fmaf(w1, a1.v[j], acc[j]);
        }
    }
    if (i < end) {
        int2 e0 = erec[i];
        if (act) {
            float w0 = __int_as_float(e0.y);
            f8 a0 = unpack8(H2b[(size_t)e0.x * 5 + q]);
#pragma unroll
            for (int j = 0; j < 8; ++j) acc[j] = fmaf(w0, a0.v[j], acc[j]);
        }
    }
    if (act) {
        float4 b0 = ((const float4*)b2)[q * 2];
        float4 b1v = ((const float4*)b2)[q * 2 + 1];
        acc[0] += b0.x; acc[1] += b0.y; acc[2] += b0.z; acc[3] += b0.w;
        acc[4] += b1v.x; acc[5] += b1v.y; acc[6] += b1v.z; acc[7] += b1v.w;
    }
    float m = -INFINITY;
    if (act) {
#pragma unroll
        for (int j = 0; j < 8; ++j) m = fmaxf(m, acc[j]);
    }
#pragma unroll
    for (int o = 4; o > 0; o >>= 1) m = fmaxf(m, __shfl_xor(m, o, 8));
    float e = 0.f;
    if (act) {
#pragma unroll
        for (int j = 0; j < 8; ++j) e += expf(acc[j] - m);
    }
#pragma unroll
    for (int o = 4; o > 0; o >>= 1) e += __shfl_xor(e, o, 8);
    float lg = m + logf(e);
    if (act) {
        float4* o4 = (float4*)out;
        o4[(size_t)n * 10 + q * 2] =
            make_float4(acc[0] - lg, acc[1] - lg, acc[2] - lg, acc[3] - lg);
        o4[(size_t)n * 10 + q * 2 + 1] =
            make_float4(acc[4] - lg, acc[5] - lg, acc[6] - lg, acc[7] - lg);
    }
}

extern "C" void kernel_launch(void* const* d_in, const int* in_sizes, int n_in,
                              void* d_out, int out_size, void* d_ws, size_t ws_size,
                              hipStream_t stream) {
    const float* x  = (const float*)d_in[0];
    const int*   ei = (const int*)d_in[1];   // integer inputs arrive as int32
    const float* W1 = (const float*)d_in[2];
    const float* b1 = (const float*)d_in[3];
    const float* W2 = (const float*)d_in[4];
    const float* b2 = (const float*)d_in[5];
    float* out = (float*)d_out;

    const int N = in_sizes[0] / 128;  // 100000
    const int E = in_sizes[1] / 2;    // 1600000
    const int nbkt = (N + RB - 1) / RB;  // 1021 (<= 1024 required)

    // workspace layout (~90 MB; ws proven >= 119 MB in round 2/3)
    char* ws = (char*)d_ws;
    int*   deg     = (int*)(ws);                          // N ints
    float* dinv    = (float*)(ws + (512 << 10));          // N f32
    int*   row_ptr = (int*)(ws + (1 << 20));              // N+1
    int*   bsum    = (int*)(ws + (1536 << 10));           // <=1024
    int*   tmp     = (int*)(ws + (1600 << 10));           // N ints
    int*   bktcnt  = (int*)(ws + (2100 << 10));           // 1024
    int*   gcur    = (int*)(ws + (2100 << 10) + 4096);    // 1024
    int*   gbase   = (int*)(ws + (2100 << 10) + 8192);    // 1025
    short* Wt1     = (short*)(ws + (2200 << 10));         // 128x128 bf16 = 32 KB
    short* Wt2     = (short*)(ws + (2300 << 10));         // 48x128 bf16 = 12 KB
    int2*  erec    = (int2*)(ws + (3 << 20));             // E int2 = 12.8 MB
    int2*  brec    = (int2*)(ws + (16 << 20));            // E int2 = 12.8 MB
    uint4* H2b     = (uint4*)(ws + (29 << 20));           // N*40 bf16 = 8 MB
    unsigned* Tb   = (unsigned*)(ws + (38 << 20));        // N*128 bf16 = 25.6 MB
    unsigned* Ub   = (unsigned*)(ws + (64 << 20));        // N*128 bf16 = 25.6 MB

    int nb = (N + 255) / 256;
    int na = (E + TILE_A - 1) / TILE_A;
    int ng = (N + 127) / 128;  // MFMA gemm blocks

    k_zero<<<4, 256, 0, stream>>>(bktcnt, 1024);
    k_prebin<<<na, 256, 0, stream>>>(ei, bktcnt, E, nbkt);
    k_bscan<<<1, 1024, 0, stream>>>(bktcnt, gbase, gcur, nbkt);
    k_binA<<<na, 256, 0, stream>>>(ei, gcur, brec, E);
    k_count3<<<nbkt, 256, 0, stream>>>(brec, gbase, deg, N);
    k_scan1<<<nb, 256, 0, stream>>>(deg, tmp, bsum, dinv, N);
    k_scan2<<<1, 1024, 0, stream>>>(bsum, nb);
    k_scan3<<<nb, 256, 0, stream>>>(deg, tmp, bsum, row_ptr, N, E);
    k_csr3<<<nbkt, 256, 0, stream>>>(brec, gbase, row_ptr, dinv, erec, N);

    k_wt1<<<64, 256, 0, stream>>>(W1, Wt1);
    k_wt2<<<24, 256, 0, stream>>>(W2, Wt2);

    k_gemm1m<<<ng, 256, 0, stream>>>(x, Wt1, (short*)Tb, N);
    k_pull1<<<((long long)N * 16 + 255) / 256, 256, 0, stream>>>(
        (const uint4*)Tb, dinv, row_ptr, erec, b1, (uint4*)Ub, N);
    k_gemm2m<<<ng, 256, 0, stream>>>((const short*)Ub, Wt2, (short*)H2b, N);
    k_pull2<<<((long long)N * 8 + 255) / 256, 256, 0, stream>>>(
        H2b, dinv, row_ptr, erec, b2, out, N);
}